// Round 14
// baseline (129.851 us; speedup 1.0000x reference)
//
#include <hip/hip_runtime.h>
#include <hip/hip_fp16.h>

#define N_NODES 100000
#define N_EDGES 1600000
#define D 32
#define EPB 4096                                   // edges per level-1 block
#define NBLK ((N_EDGES + EPB - 1) / EPB)           // 391 level-1 blocks (1.5/CU)
#define NBC ((N_NODES + 255) / 256)                // 391 coarse buckets (256 nodes each)
#define NBB (NBC * NBLK)                           // 152881 scan entries
#define SCAN_BLK 1024
#define SNB1 ((NBB + SCAN_BLK - 1) / SCAN_BLK)     // 150
#define WFX_SCALE 67108864.0f                      // 2^26 fixed point for deg

// --------------------------------------------------------------- level-1 count
__global__ void k_bcount(const int* __restrict__ dst, int* __restrict__ bhist) {
    __shared__ int hist[NBC];
    int t = threadIdx.x;
    for (int i = t; i < NBC; i += 1024) hist[i] = 0;
    __syncthreads();
    int base = blockIdx.x * EPB;
#pragma unroll
    for (int i = 0; i < 4; ++i) {
        int e = base + i * 1024 + t;
        if (e < N_EDGES) {
            int d = dst[e];
            if ((unsigned)d < N_NODES) atomicAdd(&hist[d >> 8], 1);
        }
    }
    __syncthreads();
    for (int c = t; c < NBC; c += 1024) bhist[c * NBLK + blockIdx.x] = hist[c];
}

// ----------------------------------------------------------------- scans (n)
__global__ void k_scan1(const int* __restrict__ in, int* __restrict__ incl,
                        int* __restrict__ bsum, int n) {
    __shared__ int sh[SCAN_BLK];
    int t = threadIdx.x;
    int g = blockIdx.x * SCAN_BLK + t;
    int v = (g < n) ? in[g] : 0;
    sh[t] = v;
    __syncthreads();
    for (int off = 1; off < SCAN_BLK; off <<= 1) {
        int add = (t >= off) ? sh[t - off] : 0;
        __syncthreads();
        sh[t] += add;
        __syncthreads();
    }
    if (g < n) incl[g] = sh[t];
    if (t == SCAN_BLK - 1) bsum[blockIdx.x] = sh[t];
}

__global__ void k_scan2(const int* __restrict__ bsum, int* __restrict__ boffs, int nb) {
    __shared__ int sh[1024];
    int t = threadIdx.x;
    int v = (t < nb) ? bsum[t] : 0;
    sh[t] = v;
    __syncthreads();
    for (int off = 1; off < 1024; off <<= 1) {
        int add = (t >= off) ? sh[t - off] : 0;
        __syncthreads();
        sh[t] += add;
        __syncthreads();
    }
    if (t < nb) boffs[t] = sh[t] - v;  // exclusive
}

__global__ void k_scan3(const int* __restrict__ in, const int* __restrict__ incl,
                        const int* __restrict__ boffs, int* __restrict__ outp, int n) {
    int g = blockIdx.x * 256 + threadIdx.x;
    if (g < n) outp[g] = incl[g] - in[g] + boffs[g / SCAN_BLK];
}

// -------------------------------------------------------------- level-1 scatter
// rec.x = src (bits 0..19) | dlow (bits 20..27);  rec.y = w fp32 bits
__global__ void k_bscatter(const int* __restrict__ src, const int* __restrict__ dst,
                           const float* __restrict__ w, const int* __restrict__ sbase,
                           uint2* __restrict__ bucketed) {
    __shared__ int hist[NBC];
    __shared__ int lsb[NBC];
    int t = threadIdx.x;
    for (int i = t; i < NBC; i += 1024) {
        hist[i] = 0;
        lsb[i] = sbase[i * NBLK + blockIdx.x];
    }
    __syncthreads();
    int base = blockIdx.x * EPB;
#pragma unroll
    for (int i = 0; i < 4; ++i) {
        int e = base + i * 1024 + t;
        if (e < N_EDGES) {
            int d = dst[e];
            if ((unsigned)d < N_NODES) {
                int c = d >> 8;
                int r = atomicAdd(&hist[c], 1);
                uint2 rec;
                rec.x = ((unsigned)src[e] & 0xFFFFFu) | ((unsigned)(d & 255) << 20);
                rec.y = __float_as_uint(w[e]);
                bucketed[lsb[c] + r] = rec;
            }
        }
    }
}

// ----------------------------------------------------- level-2 CSR finalization
// 512 threads/bucket. Output edge record = ONE u32: src(17b)<<15 | bf15(w).
__global__ void k_build(const int* __restrict__ sbase, const uint2* __restrict__ bucketed,
                        int* __restrict__ rowptr, float* __restrict__ dis,
                        unsigned* __restrict__ edge1) {
    __shared__ int cnt[256], lb[256], fill[256], sh[256];
    __shared__ unsigned wfx[256];
    int t = threadIdx.x, c = blockIdx.x;
    if (t < 256) { cnt[t] = 0; fill[t] = 0; wfx[t] = 0; }
    __syncthreads();
    int beg = sbase[c * NBLK];
    int end = (c == NBC - 1) ? N_EDGES : sbase[(c + 1) * NBLK];
    for (int i = beg + t; i < end; i += 512) {
        uint2 rec = bucketed[i];
        int dlow = rec.x >> 20;
        atomicAdd(&cnt[dlow], 1);
        atomicAdd(&wfx[dlow], (unsigned)(__uint_as_float(rec.y) * WFX_SCALE));
    }
    __syncthreads();
    int v = (t < 256) ? cnt[t] : 0;
    if (t < 256) sh[t] = v;
    __syncthreads();
    for (int off = 1; off < 256; off <<= 1) {
        int add = (t < 256 && t >= off) ? sh[t - off] : 0;
        __syncthreads();
        if (t < 256) sh[t] += add;
        __syncthreads();
    }
    if (t < 256) {
        int ex = sh[t] - v;
        lb[t] = ex;
        int node = c * 256 + t;
        if (node < N_NODES) {
            rowptr[node] = beg + ex;
            float deg = (float)wfx[t] * (1.0f / WFX_SCALE);
            dis[node] = rsqrtf(deg + 1.0f);
        }
    }
    if (c == 0 && t == 0) rowptr[N_NODES] = N_EDGES;
    __syncthreads();
    for (int i = beg + t; i < end; i += 512) {
        uint2 rec = bucketed[i];
        int dlow = rec.x >> 20;
        int r = atomicAdd(&fill[dlow], 1);
        unsigned b32 = rec.y;                                      // w fp32 bits, sign=0
        unsigned w15 = (b32 + 0x7FFFu + ((b32 >> 16) & 1u)) >> 16; // bf16 RNE
        edge1[beg + lb[dlow] + r] = ((rec.x & 0xFFFFFu) << 15) | (w15 & 0x7FFFu);
    }
}

// ---------------------------------------------------------------- GEMM (fp16 out)
__global__ void k_gemm32h(const float* __restrict__ X, const float* __restrict__ W,
                          const float* __restrict__ dis, __half* __restrict__ Y) {
    __shared__ float Ws[D * D];
    __shared__ float Xs[8][D];
    int t = threadIdx.x;
    for (int i = t; i < D * D; i += 256) Ws[i] = W[i];
    int local = t >> 5, j = t & 31;
    int node = blockIdx.x * 8 + local;
    if (node < N_NODES) Xs[local][j] = X[node * D + j];
    __syncthreads();
    if (node < N_NODES) {
        float acc = 0.f;
#pragma unroll
        for (int k = 0; k < D; ++k) acc = fmaf(Xs[local][k], Ws[k * D + j], acc);
        Y[(size_t)node * D + j] = __float2half(acc * dis[node]);
    }
}

// ------------------------------------------------------------- gather + fused W2
// 16-lane group per node; lane g owns features {2g, 2g+1} via __half2 loads.
// 8-deep unroll -> 32 independent edge chains per wave.
// edge1 loads are NONTEMPORAL (read-once stream, keep L2 for xm reuse).
__global__ void k_gather_mid(const int* __restrict__ rowptr, const unsigned* __restrict__ edge1,
                             const __half* __restrict__ xm, const float* __restrict__ dis,
                             const float* __restrict__ b, const float* __restrict__ W2,
                             __half* __restrict__ y) {
    __shared__ float2 W2p[D * 16];   // W2p[f*16+g] = (W2[f][2g], W2[f][2g+1])
    int t = threadIdx.x;
    for (int i = t; i < D * 16; i += 256) {
        int f = i >> 4, g = i & 15;
        W2p[i] = make_float2(W2[f * D + 2 * g], W2[f * D + 2 * g + 1]);
    }
    __syncthreads();
    int node = blockIdx.x * 16 + (t >> 4);
    if (node >= N_NODES) return;
    int g = t & 15;
    int beg = rowptr[node], end = rowptr[node + 1];
    float ax[8], ay[8];
#pragma unroll
    for (int u = 0; u < 8; ++u) { ax[u] = 0.f; ay[u] = 0.f; }
    int j = beg;
    for (; j + 7 < end; j += 8) {
#pragma unroll
        for (int u = 0; u < 8; ++u) {
            unsigned e = __builtin_nontemporal_load(&edge1[j + u]);
            float wv = __uint_as_float((e & 0x7FFFu) << 16);
            float2 xv = __half22float2(*(const __half2*)(xm + (size_t)(e >> 15) * D + 2 * g));
            ax[u] = fmaf(wv, xv.x, ax[u]);
            ay[u] = fmaf(wv, xv.y, ay[u]);
        }
    }
    for (; j + 3 < end; j += 4) {
#pragma unroll
        for (int u = 0; u < 4; ++u) {
            unsigned e = __builtin_nontemporal_load(&edge1[j + u]);
            float wv = __uint_as_float((e & 0x7FFFu) << 16);
            float2 xv = __half22float2(*(const __half2*)(xm + (size_t)(e >> 15) * D + 2 * g));
            ax[u] = fmaf(wv, xv.x, ax[u]);
            ay[u] = fmaf(wv, xv.y, ay[u]);
        }
    }
    for (; j < end; ++j) {
        unsigned e = __builtin_nontemporal_load(&edge1[j]);
        float wv = __uint_as_float((e & 0x7FFFu) << 16);
        float2 xv = __half22float2(*(const __half2*)(xm + (size_t)(e >> 15) * D + 2 * g));
        ax[0] = fmaf(wv, xv.x, ax[0]);
        ay[0] = fmaf(wv, xv.y, ay[0]);
    }
    float a0 = ((ax[0] + ax[1]) + (ax[2] + ax[3])) + ((ax[4] + ax[5]) + (ax[6] + ax[7]));
    float a1 = ((ay[0] + ay[1]) + (ay[2] + ay[3])) + ((ay[4] + ay[5]) + (ay[6] + ay[7]));
    float s = dis[node];
    float2 self = __half22float2(*(const __half2*)(xm + (size_t)node * D + 2 * g));
    float h0 = fmaxf(s * (a0 + self.x) + b[2 * g], 0.f);
    float h1 = fmaxf(s * (a1 + self.y) + b[2 * g + 1], 0.f);
    __half2 hp = __floats2half2_rn(h0, h1);
    float hpf = __uint_as_float(*(unsigned*)&hp);
    float acc0 = 0.f, acc1 = 0.f;
#pragma unroll
    for (int k = 0; k < 16; ++k) {
        float r = __shfl(hpf, k, 16);
        unsigned u = __float_as_uint(r);
        float2 hh = __half22float2(*(__half2*)&u);
        float2 wa = W2p[(2 * k) * 16 + g];
        float2 wb = W2p[(2 * k + 1) * 16 + g];
        acc0 = fmaf(hh.x, wa.x, acc0); acc1 = fmaf(hh.x, wa.y, acc1);
        acc0 = fmaf(hh.y, wb.x, acc0); acc1 = fmaf(hh.y, wb.y, acc1);
    }
    *(__half2*)(y + (size_t)node * D + 2 * g) = __floats2half2_rn(s * acc0, s * acc1);
}

// ------------------------------------------------------------------ final gather
// edge1 nontemporal; out stores nontemporal (never re-read).
__global__ void k_gather_out(const int* __restrict__ rowptr, const unsigned* __restrict__ edge1,
                             const __half* __restrict__ xm, const float* __restrict__ dis,
                             const float* __restrict__ b, float* __restrict__ out) {
    int t = threadIdx.x;
    int node = blockIdx.x * 16 + (t >> 4);
    if (node >= N_NODES) return;
    int g = t & 15;
    int beg = rowptr[node], end = rowptr[node + 1];
    float ax[8], ay[8];
#pragma unroll
    for (int u = 0; u < 8; ++u) { ax[u] = 0.f; ay[u] = 0.f; }
    int j = beg;
    for (; j + 7 < end; j += 8) {
#pragma unroll
        for (int u = 0; u < 8; ++u) {
            unsigned e = __builtin_nontemporal_load(&edge1[j + u]);
            float wv = __uint_as_float((e & 0x7FFFu) << 16);
            float2 xv = __half22float2(*(const __half2*)(xm + (size_t)(e >> 15) * D + 2 * g));
            ax[u] = fmaf(wv, xv.x, ax[u]);
            ay[u] = fmaf(wv, xv.y, ay[u]);
        }
    }
    for (; j + 3 < end; j += 4) {
#pragma unroll
        for (int u = 0; u < 4; ++u) {
            unsigned e = __builtin_nontemporal_load(&edge1[j + u]);
            float wv = __uint_as_float((e & 0x7FFFu) << 16);
            float2 xv = __half22float2(*(const __half2*)(xm + (size_t)(e >> 15) * D + 2 * g));
            ax[u] = fmaf(wv, xv.x, ax[u]);
            ay[u] = fmaf(wv, xv.y, ay[u]);
        }
    }
    for (; j < end; ++j) {
        unsigned e = __builtin_nontemporal_load(&edge1[j]);
        float wv = __uint_as_float((e & 0x7FFFu) << 16);
        float2 xv = __half22float2(*(const __half2*)(xm + (size_t)(e >> 15) * D + 2 * g));
        ax[0] = fmaf(wv, xv.x, ax[0]);
        ay[0] = fmaf(wv, xv.y, ay[0]);
    }
    float a0 = ((ax[0] + ax[1]) + (ax[2] + ax[3])) + ((ax[4] + ax[5]) + (ax[6] + ax[7]));
    float a1 = ((ay[0] + ay[1]) + (ay[2] + ay[3])) + ((ay[4] + ay[5]) + (ay[6] + ay[7]));
    float s = dis[node];
    float2 self = __half22float2(*(const __half2*)(xm + (size_t)node * D + 2 * g));
    float o0 = s * (a0 + self.x) + b[2 * g];
    float o1 = s * (a1 + self.y) + b[2 * g + 1];
    __builtin_nontemporal_store(o0, out + (size_t)node * D + 2 * g);
    __builtin_nontemporal_store(o1, out + (size_t)node * D + 2 * g + 1);
}

// ------------------------------------------------- fallback (atomic pipeline)
__global__ void k_hist(const int* __restrict__ dst, const float* __restrict__ w,
                       float* __restrict__ deg) {
    int e = blockIdx.x * blockDim.x + threadIdx.x;
    if (e < N_EDGES) {
        int d = dst[e];
        if ((unsigned)d < N_NODES) atomicAdd(&deg[d], w[e]);
    }
}

__global__ void k_disf(float* __restrict__ deg) {
    int i = blockIdx.x * blockDim.x + threadIdx.x;
    if (i < N_NODES) deg[i] = rsqrtf(deg[i] + 1.0f);
}

__global__ void k_coef(const int* __restrict__ src, const int* __restrict__ dst,
                       const float* __restrict__ w, const float* __restrict__ dis,
                       float* __restrict__ coef) {
    int e = blockIdx.x * blockDim.x + threadIdx.x;
    if (e < N_EDGES) {
        int s = src[e], d = dst[e];
        float c = 0.f;
        if ((unsigned)s < N_NODES && (unsigned)d < N_NODES)
            c = dis[s] * w[e] * dis[d];
        coef[e] = c;
    }
}

__global__ void k_gemm32f(const float* __restrict__ X, const float* __restrict__ W,
                          float* __restrict__ Y) {
    __shared__ float Ws[D * D];
    __shared__ float Xs[8][D];
    int t = threadIdx.x;
    for (int i = t; i < D * D; i += 256) Ws[i] = W[i];
    int local = t >> 5, j = t & 31;
    int node = blockIdx.x * 8 + local;
    if (node < N_NODES) Xs[local][j] = X[node * D + j];
    __syncthreads();
    if (node < N_NODES) {
        float acc = 0.f;
#pragma unroll
        for (int k = 0; k < D; ++k) acc = fmaf(Xs[local][k], Ws[k * D + j], acc);
        Y[node * D + j] = acc;
    }
}

__global__ void k_scatter(const int* __restrict__ src, const int* __restrict__ dst,
                          const float* __restrict__ coef, const float* __restrict__ xm,
                          float* __restrict__ out) {
    long long gid = (long long)blockIdx.x * blockDim.x + threadIdx.x;
    if (gid >= (long long)N_EDGES * D) return;
    int e = (int)(gid >> 5);
    int f = (int)(gid & 31);
    int s = src[e], d = dst[e];
    if ((unsigned)s >= N_NODES || (unsigned)d >= N_NODES) return;
    atomicAdd(&out[d * D + f], coef[e] * xm[s * D + f]);
}

__global__ void k_final(float* __restrict__ acc, const float* __restrict__ xm,
                        const float* __restrict__ dis, const float* __restrict__ b,
                        int do_relu) {
    int gid = blockIdx.x * blockDim.x + threadIdx.x;
    if (gid < N_NODES * D) {
        int i = gid >> 5, f = gid & 31;
        float s = dis[i];
        float v = acc[gid] + s * s * xm[gid] + b[f];
        if (do_relu) v = fmaxf(v, 0.f);
        acc[gid] = v;
    }
}

extern "C" void kernel_launch(void* const* d_in, const int* in_sizes, int n_in,
                              void* d_out, int out_size, void* d_ws, size_t ws_size,
                              hipStream_t stream) {
    const float* x  = (const float*)d_in[0];
    const int*   ei = (const int*)d_in[1];   // [2, E] flat: row 0 = src, row 1 = dst
    const float* w  = (const float*)d_in[2];
    const float* W1 = (const float*)d_in[3];
    const float* b1 = (const float*)d_in[4];
    const float* W2 = (const float*)d_in[5];
    const float* b2 = (const float*)d_in[6];
    const int* src = ei;
    const int* dst = ei + N_EDGES;
    float* out = (float*)d_out;

    // ---- workspace layout (~22 MB) ----
    char* p = (char*)d_ws;
    uint2*    bucketed = (uint2*)p;    p += (size_t)N_EDGES * 8;
    unsigned* edge1    = (unsigned*)p; p += (size_t)N_EDGES * 4;
    int*      bhist    = (int*)p;      p += (size_t)NBB * 4 + 8;
    int*      incl     = (int*)p;      p += (size_t)NBB * 4 + 8;
    int*      rowptr_s = (int*)p;      p += (size_t)(N_NODES + 2) * 4;
    float*    dis_s    = (float*)p;    p += (size_t)N_NODES * 4;
    int*      sbase    = (int*)p;      p += (size_t)NBB * 4 + 8;
    int*      bsum     = (int*)p;      p += 4096;
    int*      boffs    = (int*)p;      p += 4096;
    size_t need = (size_t)(p - (char*)d_ws);

    __half* xm1s  = (__half*)bucketed;                          // 6.4 MB (after build)
    __half* xm2s  = (__half*)bucketed + (size_t)N_NODES * D;    // next 6.4 MB
    int*    rowptr = rowptr_s;
    float*  dis    = dis_s;

    if (ws_size >= need) {
        // ---- CSR build: zero global atomics; packed u32 edge records ----
        k_bcount<<<NBLK, 1024, 0, stream>>>(dst, bhist);
        k_scan1<<<SNB1, SCAN_BLK, 0, stream>>>(bhist, incl, bsum, NBB);
        k_scan2<<<1, 1024, 0, stream>>>(bsum, boffs, SNB1);
        k_scan3<<<(NBB + 255) / 256, 256, 0, stream>>>(bhist, incl, boffs, sbase, NBB);
        k_bscatter<<<NBLK, 1024, 0, stream>>>(src, dst, w, sbase, bucketed);
        k_build<<<NBC, 512, 0, stream>>>(sbase, bucketed, rowptr, dis, edge1);

        // ---- layer 1 GEMM: xm1s = dis * (x @ W1), fp16 (overwrites bucketed) ----
        k_gemm32h<<<(N_NODES + 7) / 8, 256, 0, stream>>>(x, W1, dis, xm1s);
        // ---- gather1 + bias/relu + fused @W2 + dis-scale -> xm2s fp16 ----
        k_gather_mid<<<(N_NODES + 15) / 16, 256, 0, stream>>>(rowptr, edge1, xm1s, dis, b1, W2, xm2s);
        // ---- gather2 + bias -> out fp32 ----
        k_gather_out<<<(N_NODES + 15) / 16, 256, 0, stream>>>(rowptr, edge1, xm2s, dis, b2, out);
    } else {
        // ---- fallback: atomic-scatter pipeline (ws >= ~33 MB) ----
        float* fdis  = (float*)d_ws;
        float* coef  = fdis + N_NODES;
        float* fxm   = coef + N_EDGES;
        float* fh    = fxm + (size_t)N_NODES * D;

        hipMemsetAsync(fdis, 0, N_NODES * sizeof(float), stream);
        k_hist<<<(N_EDGES + 255) / 256, 256, 0, stream>>>(dst, w, fdis);
        k_disf<<<(N_NODES + 255) / 256, 256, 0, stream>>>(fdis);
        k_coef<<<(N_EDGES + 255) / 256, 256, 0, stream>>>(src, dst, w, fdis, coef);

        k_gemm32f<<<(N_NODES + 7) / 8, 256, 0, stream>>>(x, W1, fxm);
        hipMemsetAsync(fh, 0, (size_t)N_NODES * D * sizeof(float), stream);
        k_scatter<<<(int)(((long long)N_EDGES * D + 255) / 256), 256, 0, stream>>>(src, dst, coef, fxm, fh);
        k_final<<<(N_NODES * D + 255) / 256, 256, 0, stream>>>(fh, fxm, fdis, b1, 1);

        k_gemm32f<<<(N_NODES + 7) / 8, 256, 0, stream>>>(fh, W2, fxm);
        hipMemsetAsync(out, 0, (size_t)out_size * sizeof(float), stream);
        k_scatter<<<(int)(((long long)N_EDGES * D + 255) / 256), 256, 0, stream>>>(src, dst, coef, fxm, out);
        k_final<<<(N_NODES * D + 255) / 256, 256, 0, stream>>>(out, fxm, fdis, b2, 0);
    }
}

// Round 15
// 120.882 us; speedup vs baseline: 1.0742x; 1.0742x over previous
//
#include <hip/hip_runtime.h>
#include <hip/hip_fp16.h>

#define N_NODES 100000
#define N_EDGES 1600000
#define D 32
#define EPB 4096                                   // edges per level-1 block
#define NBLK ((N_EDGES + EPB - 1) / EPB)           // 391 level-1 blocks (1.5/CU)
#define NBC ((N_NODES + 255) / 256)                // 391 coarse buckets (256 nodes each)
#define NBB (NBC * NBLK)                           // 152881 scan entries
#define SCAN_BLK 1024
#define SNB1 ((NBB + SCAN_BLK - 1) / SCAN_BLK)     // 150
#define WFX_SCALE 67108864.0f                      // 2^26 fixed point for deg

// --------------------------------------------------------------- level-1 count
__global__ void k_bcount(const int* __restrict__ dst, int* __restrict__ bhist) {
    __shared__ int hist[NBC];
    int t = threadIdx.x;
    for (int i = t; i < NBC; i += 1024) hist[i] = 0;
    __syncthreads();
    int base = blockIdx.x * EPB;
#pragma unroll
    for (int i = 0; i < 4; ++i) {
        int e = base + i * 1024 + t;
        if (e < N_EDGES) {
            int d = dst[e];
            if ((unsigned)d < N_NODES) atomicAdd(&hist[d >> 8], 1);
        }
    }
    __syncthreads();
    for (int c = t; c < NBC; c += 1024) bhist[c * NBLK + blockIdx.x] = hist[c];
}

// ----------------------------------------------------------------- scans (n)
__global__ void k_scan1(const int* __restrict__ in, int* __restrict__ incl,
                        int* __restrict__ bsum, int n) {
    __shared__ int sh[SCAN_BLK];
    int t = threadIdx.x;
    int g = blockIdx.x * SCAN_BLK + t;
    int v = (g < n) ? in[g] : 0;
    sh[t] = v;
    __syncthreads();
    for (int off = 1; off < SCAN_BLK; off <<= 1) {
        int add = (t >= off) ? sh[t - off] : 0;
        __syncthreads();
        sh[t] += add;
        __syncthreads();
    }
    if (g < n) incl[g] = sh[t];
    if (t == SCAN_BLK - 1) bsum[blockIdx.x] = sh[t];
}

__global__ void k_scan2(const int* __restrict__ bsum, int* __restrict__ boffs, int nb) {
    __shared__ int sh[1024];
    int t = threadIdx.x;
    int v = (t < nb) ? bsum[t] : 0;
    sh[t] = v;
    __syncthreads();
    for (int off = 1; off < 1024; off <<= 1) {
        int add = (t >= off) ? sh[t - off] : 0;
        __syncthreads();
        sh[t] += add;
        __syncthreads();
    }
    if (t < nb) boffs[t] = sh[t] - v;  // exclusive
}

__global__ void k_scan3(const int* __restrict__ in, const int* __restrict__ incl,
                        const int* __restrict__ boffs, int* __restrict__ outp, int n) {
    int g = blockIdx.x * 256 + threadIdx.x;
    if (g < n) outp[g] = incl[g] - in[g] + boffs[g / SCAN_BLK];
}

// -------------------------------------------------------------- level-1 scatter
// rec.x = src (bits 0..19) | dlow (bits 20..27);  rec.y = w fp32 bits
__global__ void k_bscatter(const int* __restrict__ src, const int* __restrict__ dst,
                           const float* __restrict__ w, const int* __restrict__ sbase,
                           uint2* __restrict__ bucketed) {
    __shared__ int hist[NBC];
    __shared__ int lsb[NBC];
    int t = threadIdx.x;
    for (int i = t; i < NBC; i += 1024) {
        hist[i] = 0;
        lsb[i] = sbase[i * NBLK + blockIdx.x];
    }
    __syncthreads();
    int base = blockIdx.x * EPB;
#pragma unroll
    for (int i = 0; i < 4; ++i) {
        int e = base + i * 1024 + t;
        if (e < N_EDGES) {
            int d = dst[e];
            if ((unsigned)d < N_NODES) {
                int c = d >> 8;
                int r = atomicAdd(&hist[c], 1);
                uint2 rec;
                rec.x = ((unsigned)src[e] & 0xFFFFFu) | ((unsigned)(d & 255) << 20);
                rec.y = __float_as_uint(w[e]);
                bucketed[lsb[c] + r] = rec;
            }
        }
    }
}

// ----------------------------------------------------- level-2 CSR finalization
// 512 threads/bucket. Output edge record = ONE u32: src(17b)<<15 | bf15(w).
__global__ void k_build(const int* __restrict__ sbase, const uint2* __restrict__ bucketed,
                        int* __restrict__ rowptr, float* __restrict__ dis,
                        unsigned* __restrict__ edge1) {
    __shared__ int cnt[256], lb[256], fill[256], sh[256];
    __shared__ unsigned wfx[256];
    int t = threadIdx.x, c = blockIdx.x;
    if (t < 256) { cnt[t] = 0; fill[t] = 0; wfx[t] = 0; }
    __syncthreads();
    int beg = sbase[c * NBLK];
    int end = (c == NBC - 1) ? N_EDGES : sbase[(c + 1) * NBLK];
    for (int i = beg + t; i < end; i += 512) {
        uint2 rec = bucketed[i];
        int dlow = rec.x >> 20;
        atomicAdd(&cnt[dlow], 1);
        atomicAdd(&wfx[dlow], (unsigned)(__uint_as_float(rec.y) * WFX_SCALE));
    }
    __syncthreads();
    int v = (t < 256) ? cnt[t] : 0;
    if (t < 256) sh[t] = v;
    __syncthreads();
    for (int off = 1; off < 256; off <<= 1) {
        int add = (t < 256 && t >= off) ? sh[t - off] : 0;
        __syncthreads();
        if (t < 256) sh[t] += add;
        __syncthreads();
    }
    if (t < 256) {
        int ex = sh[t] - v;
        lb[t] = ex;
        int node = c * 256 + t;
        if (node < N_NODES) {
            rowptr[node] = beg + ex;
            float deg = (float)wfx[t] * (1.0f / WFX_SCALE);
            dis[node] = rsqrtf(deg + 1.0f);
        }
    }
    if (c == 0 && t == 0) rowptr[N_NODES] = N_EDGES;
    __syncthreads();
    for (int i = beg + t; i < end; i += 512) {
        uint2 rec = bucketed[i];
        int dlow = rec.x >> 20;
        int r = atomicAdd(&fill[dlow], 1);
        unsigned b32 = rec.y;                                      // w fp32 bits, sign=0
        unsigned w15 = (b32 + 0x7FFFu + ((b32 >> 16) & 1u)) >> 16; // bf16 RNE
        edge1[beg + lb[dlow] + r] = ((rec.x & 0xFFFFFu) << 15) | (w15 & 0x7FFFu);
    }
}

// ---------------------------------------------------------------- GEMM (fp16 out)
__global__ void k_gemm32h(const float* __restrict__ X, const float* __restrict__ W,
                          const float* __restrict__ dis, __half* __restrict__ Y) {
    __shared__ float Ws[D * D];
    __shared__ float Xs[8][D];
    int t = threadIdx.x;
    for (int i = t; i < D * D; i += 256) Ws[i] = W[i];
    int local = t >> 5, j = t & 31;
    int node = blockIdx.x * 8 + local;
    if (node < N_NODES) Xs[local][j] = X[node * D + j];
    __syncthreads();
    if (node < N_NODES) {
        float acc = 0.f;
#pragma unroll
        for (int k = 0; k < D; ++k) acc = fmaf(Xs[local][k], Ws[k * D + j], acc);
        Y[(size_t)node * D + j] = __float2half(acc * dis[node]);
    }
}

// ------------------------------------------------------------- gather + fused W2
// 16-lane group per node; lane g owns features {2g, 2g+1} via __half2 loads.
// 8-deep unroll -> 32 independent edge chains per wave. Plain (cached) loads:
// nt loads regressed (broadcast + shared cachelines need L2 allocation).
__global__ void k_gather_mid(const int* __restrict__ rowptr, const unsigned* __restrict__ edge1,
                             const __half* __restrict__ xm, const float* __restrict__ dis,
                             const float* __restrict__ b, const float* __restrict__ W2,
                             __half* __restrict__ y) {
    __shared__ float2 W2p[D * 16];   // W2p[f*16+g] = (W2[f][2g], W2[f][2g+1])
    int t = threadIdx.x;
    for (int i = t; i < D * 16; i += 256) {
        int f = i >> 4, g = i & 15;
        W2p[i] = make_float2(W2[f * D + 2 * g], W2[f * D + 2 * g + 1]);
    }
    __syncthreads();
    int node = blockIdx.x * 16 + (t >> 4);
    if (node >= N_NODES) return;
    int g = t & 15;
    int beg = rowptr[node], end = rowptr[node + 1];
    float ax[8], ay[8];
#pragma unroll
    for (int u = 0; u < 8; ++u) { ax[u] = 0.f; ay[u] = 0.f; }
    int j = beg;
    for (; j + 7 < end; j += 8) {
#pragma unroll
        for (int u = 0; u < 8; ++u) {
            unsigned e = edge1[j + u];
            float wv = __uint_as_float((e & 0x7FFFu) << 16);
            float2 xv = __half22float2(*(const __half2*)(xm + (size_t)(e >> 15) * D + 2 * g));
            ax[u] = fmaf(wv, xv.x, ax[u]);
            ay[u] = fmaf(wv, xv.y, ay[u]);
        }
    }
    for (; j + 3 < end; j += 4) {
#pragma unroll
        for (int u = 0; u < 4; ++u) {
            unsigned e = edge1[j + u];
            float wv = __uint_as_float((e & 0x7FFFu) << 16);
            float2 xv = __half22float2(*(const __half2*)(xm + (size_t)(e >> 15) * D + 2 * g));
            ax[u] = fmaf(wv, xv.x, ax[u]);
            ay[u] = fmaf(wv, xv.y, ay[u]);
        }
    }
    for (; j < end; ++j) {
        unsigned e = edge1[j];
        float wv = __uint_as_float((e & 0x7FFFu) << 16);
        float2 xv = __half22float2(*(const __half2*)(xm + (size_t)(e >> 15) * D + 2 * g));
        ax[0] = fmaf(wv, xv.x, ax[0]);
        ay[0] = fmaf(wv, xv.y, ay[0]);
    }
    float a0 = ((ax[0] + ax[1]) + (ax[2] + ax[3])) + ((ax[4] + ax[5]) + (ax[6] + ax[7]));
    float a1 = ((ay[0] + ay[1]) + (ay[2] + ay[3])) + ((ay[4] + ay[5]) + (ay[6] + ay[7]));
    float s = dis[node];
    float2 self = __half22float2(*(const __half2*)(xm + (size_t)node * D + 2 * g));
    float h0 = fmaxf(s * (a0 + self.x) + b[2 * g], 0.f);
    float h1 = fmaxf(s * (a1 + self.y) + b[2 * g + 1], 0.f);
    __half2 hp = __floats2half2_rn(h0, h1);
    float hpf = __uint_as_float(*(unsigned*)&hp);
    float acc0 = 0.f, acc1 = 0.f;
#pragma unroll
    for (int k = 0; k < 16; ++k) {
        float r = __shfl(hpf, k, 16);
        unsigned u = __float_as_uint(r);
        float2 hh = __half22float2(*(__half2*)&u);
        float2 wa = W2p[(2 * k) * 16 + g];
        float2 wb = W2p[(2 * k + 1) * 16 + g];
        acc0 = fmaf(hh.x, wa.x, acc0); acc1 = fmaf(hh.x, wa.y, acc1);
        acc0 = fmaf(hh.y, wb.x, acc0); acc1 = fmaf(hh.y, wb.y, acc1);
    }
    *(__half2*)(y + (size_t)node * D + 2 * g) = __floats2half2_rn(s * acc0, s * acc1);
}

// ------------------------------------------------------------------ final gather
// Plain edge1/xm loads; out stores NONTEMPORAL only (write-once, never re-read,
// each line written whole by one lane-group -> no sharing hazard).
__global__ void k_gather_out(const int* __restrict__ rowptr, const unsigned* __restrict__ edge1,
                             const __half* __restrict__ xm, const float* __restrict__ dis,
                             const float* __restrict__ b, float* __restrict__ out) {
    int t = threadIdx.x;
    int node = blockIdx.x * 16 + (t >> 4);
    if (node >= N_NODES) return;
    int g = t & 15;
    int beg = rowptr[node], end = rowptr[node + 1];
    float ax[8], ay[8];
#pragma unroll
    for (int u = 0; u < 8; ++u) { ax[u] = 0.f; ay[u] = 0.f; }
    int j = beg;
    for (; j + 7 < end; j += 8) {
#pragma unroll
        for (int u = 0; u < 8; ++u) {
            unsigned e = edge1[j + u];
            float wv = __uint_as_float((e & 0x7FFFu) << 16);
            float2 xv = __half22float2(*(const __half2*)(xm + (size_t)(e >> 15) * D + 2 * g));
            ax[u] = fmaf(wv, xv.x, ax[u]);
            ay[u] = fmaf(wv, xv.y, ay[u]);
        }
    }
    for (; j + 3 < end; j += 4) {
#pragma unroll
        for (int u = 0; u < 4; ++u) {
            unsigned e = edge1[j + u];
            float wv = __uint_as_float((e & 0x7FFFu) << 16);
            float2 xv = __half22float2(*(const __half2*)(xm + (size_t)(e >> 15) * D + 2 * g));
            ax[u] = fmaf(wv, xv.x, ax[u]);
            ay[u] = fmaf(wv, xv.y, ay[u]);
        }
    }
    for (; j < end; ++j) {
        unsigned e = edge1[j];
        float wv = __uint_as_float((e & 0x7FFFu) << 16);
        float2 xv = __half22float2(*(const __half2*)(xm + (size_t)(e >> 15) * D + 2 * g));
        ax[0] = fmaf(wv, xv.x, ax[0]);
        ay[0] = fmaf(wv, xv.y, ay[0]);
    }
    float a0 = ((ax[0] + ax[1]) + (ax[2] + ax[3])) + ((ax[4] + ax[5]) + (ax[6] + ax[7]));
    float a1 = ((ay[0] + ay[1]) + (ay[2] + ay[3])) + ((ay[4] + ay[5]) + (ay[6] + ay[7]));
    float s = dis[node];
    float2 self = __half22float2(*(const __half2*)(xm + (size_t)node * D + 2 * g));
    float o0 = s * (a0 + self.x) + b[2 * g];
    float o1 = s * (a1 + self.y) + b[2 * g + 1];
    __builtin_nontemporal_store(o0, out + (size_t)node * D + 2 * g);
    __builtin_nontemporal_store(o1, out + (size_t)node * D + 2 * g + 1);
}

// ------------------------------------------------- fallback (atomic pipeline)
__global__ void k_hist(const int* __restrict__ dst, const float* __restrict__ w,
                       float* __restrict__ deg) {
    int e = blockIdx.x * blockDim.x + threadIdx.x;
    if (e < N_EDGES) {
        int d = dst[e];
        if ((unsigned)d < N_NODES) atomicAdd(&deg[d], w[e]);
    }
}

__global__ void k_disf(float* __restrict__ deg) {
    int i = blockIdx.x * blockDim.x + threadIdx.x;
    if (i < N_NODES) deg[i] = rsqrtf(deg[i] + 1.0f);
}

__global__ void k_coef(const int* __restrict__ src, const int* __restrict__ dst,
                       const float* __restrict__ w, const float* __restrict__ dis,
                       float* __restrict__ coef) {
    int e = blockIdx.x * blockDim.x + threadIdx.x;
    if (e < N_EDGES) {
        int s = src[e], d = dst[e];
        float c = 0.f;
        if ((unsigned)s < N_NODES && (unsigned)d < N_NODES)
            c = dis[s] * w[e] * dis[d];
        coef[e] = c;
    }
}

__global__ void k_gemm32f(const float* __restrict__ X, const float* __restrict__ W,
                          float* __restrict__ Y) {
    __shared__ float Ws[D * D];
    __shared__ float Xs[8][D];
    int t = threadIdx.x;
    for (int i = t; i < D * D; i += 256) Ws[i] = W[i];
    int local = t >> 5, j = t & 31;
    int node = blockIdx.x * 8 + local;
    if (node < N_NODES) Xs[local][j] = X[node * D + j];
    __syncthreads();
    if (node < N_NODES) {
        float acc = 0.f;
#pragma unroll
        for (int k = 0; k < D; ++k) acc = fmaf(Xs[local][k], Ws[k * D + j], acc);
        Y[node * D + j] = acc;
    }
}

__global__ void k_scatter(const int* __restrict__ src, const int* __restrict__ dst,
                          const float* __restrict__ coef, const float* __restrict__ xm,
                          float* __restrict__ out) {
    long long gid = (long long)blockIdx.x * blockDim.x + threadIdx.x;
    if (gid >= (long long)N_EDGES * D) return;
    int e = (int)(gid >> 5);
    int f = (int)(gid & 31);
    int s = src[e], d = dst[e];
    if ((unsigned)s >= N_NODES || (unsigned)d >= N_NODES) return;
    atomicAdd(&out[d * D + f], coef[e] * xm[s * D + f]);
}

__global__ void k_final(float* __restrict__ acc, const float* __restrict__ xm,
                        const float* __restrict__ dis, const float* __restrict__ b,
                        int do_relu) {
    int gid = blockIdx.x * blockDim.x + threadIdx.x;
    if (gid < N_NODES * D) {
        int i = gid >> 5, f = gid & 31;
        float s = dis[i];
        float v = acc[gid] + s * s * xm[gid] + b[f];
        if (do_relu) v = fmaxf(v, 0.f);
        acc[gid] = v;
    }
}

extern "C" void kernel_launch(void* const* d_in, const int* in_sizes, int n_in,
                              void* d_out, int out_size, void* d_ws, size_t ws_size,
                              hipStream_t stream) {
    const float* x  = (const float*)d_in[0];
    const int*   ei = (const int*)d_in[1];   // [2, E] flat: row 0 = src, row 1 = dst
    const float* w  = (const float*)d_in[2];
    const float* W1 = (const float*)d_in[3];
    const float* b1 = (const float*)d_in[4];
    const float* W2 = (const float*)d_in[5];
    const float* b2 = (const float*)d_in[6];
    const int* src = ei;
    const int* dst = ei + N_EDGES;
    float* out = (float*)d_out;

    // ---- workspace layout (~22 MB) ----
    char* p = (char*)d_ws;
    uint2*    bucketed = (uint2*)p;    p += (size_t)N_EDGES * 8;
    unsigned* edge1    = (unsigned*)p; p += (size_t)N_EDGES * 4;
    int*      bhist    = (int*)p;      p += (size_t)NBB * 4 + 8;
    int*      incl     = (int*)p;      p += (size_t)NBB * 4 + 8;
    int*      rowptr_s = (int*)p;      p += (size_t)(N_NODES + 2) * 4;
    float*    dis_s    = (float*)p;    p += (size_t)N_NODES * 4;
    int*      sbase    = (int*)p;      p += (size_t)NBB * 4 + 8;
    int*      bsum     = (int*)p;      p += 4096;
    int*      boffs    = (int*)p;      p += 4096;
    size_t need = (size_t)(p - (char*)d_ws);

    __half* xm1s  = (__half*)bucketed;                          // 6.4 MB (after build)
    __half* xm2s  = (__half*)bucketed + (size_t)N_NODES * D;    // next 6.4 MB
    int*    rowptr = rowptr_s;
    float*  dis    = dis_s;

    if (ws_size >= need) {
        // ---- CSR build: zero global atomics; packed u32 edge records ----
        k_bcount<<<NBLK, 1024, 0, stream>>>(dst, bhist);
        k_scan1<<<SNB1, SCAN_BLK, 0, stream>>>(bhist, incl, bsum, NBB);
        k_scan2<<<1, 1024, 0, stream>>>(bsum, boffs, SNB1);
        k_scan3<<<(NBB + 255) / 256, 256, 0, stream>>>(bhist, incl, boffs, sbase, NBB);
        k_bscatter<<<NBLK, 1024, 0, stream>>>(src, dst, w, sbase, bucketed);
        k_build<<<NBC, 512, 0, stream>>>(sbase, bucketed, rowptr, dis, edge1);

        // ---- layer 1 GEMM: xm1s = dis * (x @ W1), fp16 (overwrites bucketed) ----
        k_gemm32h<<<(N_NODES + 7) / 8, 256, 0, stream>>>(x, W1, dis, xm1s);
        // ---- gather1 + bias/relu + fused @W2 + dis-scale -> xm2s fp16 ----
        k_gather_mid<<<(N_NODES + 15) / 16, 256, 0, stream>>>(rowptr, edge1, xm1s, dis, b1, W2, xm2s);
        // ---- gather2 + bias -> out fp32 ----
        k_gather_out<<<(N_NODES + 15) / 16, 256, 0, stream>>>(rowptr, edge1, xm2s, dis, b2, out);
    } else {
        // ---- fallback: atomic-scatter pipeline (ws >= ~33 MB) ----
        float* fdis  = (float*)d_ws;
        float* coef  = fdis + N_NODES;
        float* fxm   = coef + N_EDGES;
        float* fh    = fxm + (size_t)N_NODES * D;

        hipMemsetAsync(fdis, 0, N_NODES * sizeof(float), stream);
        k_hist<<<(N_EDGES + 255) / 256, 256, 0, stream>>>(dst, w, fdis);
        k_disf<<<(N_NODES + 255) / 256, 256, 0, stream>>>(fdis);
        k_coef<<<(N_EDGES + 255) / 256, 256, 0, stream>>>(src, dst, w, fdis, coef);

        k_gemm32f<<<(N_NODES + 7) / 8, 256, 0, stream>>>(x, W1, fxm);
        hipMemsetAsync(fh, 0, (size_t)N_NODES * D * sizeof(float), stream);
        k_scatter<<<(int)(((long long)N_EDGES * D + 255) / 256), 256, 0, stream>>>(src, dst, coef, fxm, fh);
        k_final<<<(N_NODES * D + 255) / 256, 256, 0, stream>>>(fh, fxm, fdis, b1, 1);

        k_gemm32f<<<(N_NODES + 7) / 8, 256, 0, stream>>>(fh, W2, fxm);
        hipMemsetAsync(out, 0, (size_t)out_size * sizeof(float), stream);
        k_scatter<<<(int)(((long long)N_EDGES * D + 255) / 256), 256, 0, stream>>>(src, dst, coef, fxm, out);
        k_final<<<(N_NODES * D + 255) / 256, 256, 0, stream>>>(out, fxm, fdis, b2, 0);
    }
}